// Round 2
// baseline (881.960 us; speedup 1.0000x reference)
//
#include <hip/hip_runtime.h>

// Convoluzione: VALID 3x3 cross-correlation, NCHW, fp32.
// img  [32,128,56,56], filtro [256,128,3,3] -> out [32,256,54,54]

#define BB   32
#define CIN  128
#define COUT 256
#define HH   56
#define WW   56
#define OH   54
#define OW   54

#define COB  16   // c_out per block
#define TH   6    // output rows per block (54 = 9*6)
#define CIB  2    // c_in channels staged per barrier
#define IR   (TH + 2)  // input rows needed = 8

// Block: 256 threads. tx = tid&63 -> x column (0..53 active), tg = tid>>6 ->
// which c_out quartet (4 waves x 4 c_out = 16 c_out per block).
__global__ __launch_bounds__(256) void conv3x3_fp32(
    const float* __restrict__ img,
    const float* __restrict__ flt,
    float* __restrict__ out)
{
    __shared__ float si[CIB][IR][WW];   // staged input rows   (2*8*56*4 = 3584 B)
    __shared__ float sf[CIB][COB][9];   // staged filters      (2*16*9*4 = 1152 B)

    const int tid = threadIdx.x;
    const int tx  = tid & 63;
    const int tg  = tid >> 6;

    int bid = blockIdx.x;
    const int ytile = bid % (OH / TH);  bid /= (OH / TH);
    const int cob   = bid % (COUT / COB); bid /= (COUT / COB);
    const int b     = bid;

    const int y0  = ytile * TH;
    const int co0 = cob * COB;

    float acc[4][TH];
    #pragma unroll
    for (int c = 0; c < 4; ++c)
        #pragma unroll
        for (int y = 0; y < TH; ++y) acc[c][y] = 0.0f;

    for (int ci0 = 0; ci0 < CIN; ci0 += CIB) {
        // ---- stage input: CIB * IR rows * 14 float4 per row (rows are 16B-aligned: 224 B) ----
        for (int i = tid; i < CIB * IR * (WW / 4); i += 256) {
            const int cil = i / (IR * (WW / 4));
            int rem = i - cil * (IR * (WW / 4));
            const int r = rem / (WW / 4);
            const int v = rem - r * (WW / 4);
            const float4* src = reinterpret_cast<const float4*>(
                img + (((size_t)b * CIN + (ci0 + cil)) * HH + (y0 + r)) * WW) + v;
            reinterpret_cast<float4*>(&si[cil][r][0])[v] = *src;
        }
        // ---- stage filters: CIB * COB * 9 floats ----
        for (int i = tid; i < CIB * COB * 9; i += 256) {
            const int cil = i / (COB * 9);
            int rem = i - cil * (COB * 9);
            const int col = rem / 9;
            const int e   = rem - col * 9;
            sf[cil][col][e] = flt[(((size_t)(co0 + col)) * CIN + (ci0 + cil)) * 9 + e];
        }
        __syncthreads();

        if (tx < OW) {
            #pragma unroll
            for (int cil = 0; cil < CIB; ++cil) {
                // filters for my 4 c_out into registers (LDS broadcast reads)
                float f[4][9];
                #pragma unroll
                for (int c = 0; c < 4; ++c)
                    #pragma unroll
                    for (int e = 0; e < 9; ++e)
                        f[c][e] = sf[cil][tg * 4 + c][e];
                // my 8x3 input window into registers
                float a[IR][3];
                #pragma unroll
                for (int r = 0; r < IR; ++r) {
                    a[r][0] = si[cil][r][tx + 0];
                    a[r][1] = si[cil][r][tx + 1];
                    a[r][2] = si[cil][r][tx + 2];
                }
                // 4 c_out * 6 rows * 9 taps = 216 FMA per staged channel
                #pragma unroll
                for (int y = 0; y < TH; ++y)
                    #pragma unroll
                    for (int dy = 0; dy < 3; ++dy)
                        #pragma unroll
                        for (int c = 0; c < 4; ++c)
                            acc[c][y] = fmaf(a[y + dy][0], f[c][dy * 3 + 0],
                                        fmaf(a[y + dy][1], f[c][dy * 3 + 1],
                                        fmaf(a[y + dy][2], f[c][dy * 3 + 2], acc[c][y])));
            }
        }
        __syncthreads();
    }

    if (tx < OW) {
        #pragma unroll
        for (int c = 0; c < 4; ++c) {
            const int co = co0 + tg * 4 + c;
            #pragma unroll
            for (int y = 0; y < TH; ++y) {
                out[(((size_t)b * COUT + co) * OH + (y0 + y)) * OW + tx] = acc[c][y];
            }
        }
    }
}

extern "C" void kernel_launch(void* const* d_in, const int* in_sizes, int n_in,
                              void* d_out, int out_size, void* d_ws, size_t ws_size,
                              hipStream_t stream) {
    const float* img = (const float*)d_in[0];
    const float* flt = (const float*)d_in[1];
    float* out = (float*)d_out;

    const int grid = BB * (COUT / COB) * (OH / TH);  // 32*16*9 = 4608
    conv3x3_fp32<<<grid, 256, 0, stream>>>(img, flt, out);
}

// Round 3
// 147.335 us; speedup vs baseline: 5.9861x; 5.9861x over previous
//
#include <hip/hip_runtime.h>

// Convoluzione: VALID 3x3 cross-correlation, NCHW.
// img [32,128,56,56] f32, filtro [256,128,3,3] f32 -> out [32,256,54,54] f32
// Strategy: bf16 MFMA implicit shift-conv. Filters split hi/lo bf16 (2-pass),
// img single bf16. Prep kernels build channels-last copies in d_ws.

#define BB   32
#define CIN  128
#define COUT 256
#define HH   56
#define WW   56
#define OH   54
#define OW   54

typedef short bf16x8 __attribute__((ext_vector_type(8)));
typedef float f32x4  __attribute__((ext_vector_type(4)));
typedef unsigned short u16x8 __attribute__((ext_vector_type(8)));

static __device__ __forceinline__ unsigned short f2bf(float f) {
    // round-to-nearest-even bf16
    unsigned int u = __float_as_uint(f);
    u += 0x7FFFu + ((u >> 16) & 1u);
    return (unsigned short)(u >> 16);
}
static __device__ __forceinline__ float bf2f(unsigned short h) {
    return __uint_as_float(((unsigned int)h) << 16);
}

// ---------------- prep 1: img f32 NCHW -> imgT bf16 [b][y][x][ci] ----------
__global__ __launch_bounds__(256) void prep_img(const float* __restrict__ img,
                                                unsigned short* __restrict__ imgT) {
    const int b = blockIdx.x / HH;
    const int y = blockIdx.x - b * HH;
    for (int i = threadIdx.x; i < 16 * WW; i += 256) {
        const int g = i / WW;            // ci-oct 0..15
        const int x = i - g * WW;
        unsigned short pk[8];
        #pragma unroll
        for (int j = 0; j < 8; ++j)
            pk[j] = f2bf(img[((size_t)(b * CIN + g * 8 + j) * HH + y) * WW + x]);
        *(u16x8*)(imgT + ((size_t)(b * HH + y) * WW + x) * CIN + g * 8) = *(u16x8*)pk;
    }
}

// ---------------- prep 2: filtro f32 OIHW -> filtT bf16 [t*2+p][co][ci] -----
__global__ __launch_bounds__(256) void prep_flt(const float* __restrict__ flt,
                                                unsigned short* __restrict__ filtT) {
    const int idx = blockIdx.x * 256 + threadIdx.x;   // 0..32767
    const int co = idx >> 7;
    const int ci = idx & 127;
    float v[9];
    #pragma unroll
    for (int t = 0; t < 9; ++t) v[t] = flt[(size_t)(co * CIN + ci) * 9 + t];
    #pragma unroll
    for (int t = 0; t < 9; ++t) {
        unsigned short h = f2bf(v[t]);
        unsigned short l = f2bf(v[t] - bf2f(h));
        filtT[((size_t)(t * 2 + 0) * COUT + co) * CIN + ci] = h;
        filtT[((size_t)(t * 2 + 1) * COUT + co) * CIN + ci] = l;
    }
}

// ---------------- conv kernel ----------------------------------------------
// Block: 256 thr / 4 waves. Tile: 32 co x 8 rows x 56 cols (54 + 2 pad).
// Wave w: rows (2w, 2w+1); per wave 2 m-frags (co 32) x 7 n-frags (8x2 spatial).
// LDS img: 4 ci-oct planes x 10 rows x 58 cols x 16B  (x-stride 16B: conflict-free)
// LDS flt: 4 ci-oct planes x 10 tp-slots x 32 co x 16B (tap-split staging 5+4)
#define COT   32
#define RS    8
#define IMG_ROW   928            // 58*16
#define IMG_PLANE 9280           // 10*928
#define FLT_OFF   37120          // 4*9280
#define FLT_PLANE 5120           // 10*32*16
#define LDS_BYTES 57600          // 37120 + 4*5120

template<int T0, int T1, int TS>
static __device__ __forceinline__ void compute_taps(const char* bA, const char* bB,
                                                    f32x4 acc[2][7]) {
    #pragma unroll
    for (int t = T0; t < T1; ++t) {
        const int dy = t / 3, dx = t % 3;
        const int tpl = (t - TS) * 2;
        bf16x8 ah0 = *(const bf16x8*)(bA + (tpl + 0) * 512 + 0);
        bf16x8 ah1 = *(const bf16x8*)(bA + (tpl + 0) * 512 + 256);
        bf16x8 al0 = *(const bf16x8*)(bA + (tpl + 1) * 512 + 0);
        bf16x8 al1 = *(const bf16x8*)(bA + (tpl + 1) * 512 + 256);
        #pragma unroll
        for (int nf = 0; nf < 7; ++nf) {
            bf16x8 bv = *(const bf16x8*)(bB + dy * IMG_ROW + (nf * 8 + dx) * 16);
            acc[0][nf] = __builtin_amdgcn_mfma_f32_16x16x32_bf16(ah0, bv, acc[0][nf], 0, 0, 0);
            acc[1][nf] = __builtin_amdgcn_mfma_f32_16x16x32_bf16(ah1, bv, acc[1][nf], 0, 0, 0);
            acc[0][nf] = __builtin_amdgcn_mfma_f32_16x16x32_bf16(al0, bv, acc[0][nf], 0, 0, 0);
            acc[1][nf] = __builtin_amdgcn_mfma_f32_16x16x32_bf16(al1, bv, acc[1][nf], 0, 0, 0);
        }
    }
}

__global__ __launch_bounds__(256, 2) void conv_mfma(
    const unsigned short* __restrict__ imgT,
    const unsigned short* __restrict__ filtT,
    float* __restrict__ out)
{
    __shared__ char lds[LDS_BYTES];

    const int tid  = threadIdx.x;
    const int lane = tid & 63, wv = tid >> 6;
    const int sub  = lane & 15, kg = lane >> 4;
    const int ysub = sub >> 3,  xl = sub & 7;

    // XCD-aware swizzle (1792 = 8*224, bijective)
    const int w    = (blockIdx.x & 7) * 224 + (blockIdx.x >> 3);
    const int cot  = w & 7;
    const int rest = w >> 3;
    const int strip = rest % 7;
    const int b     = rest / 7;
    const int co0   = cot * COT;
    const int ystart = (strip < 6) ? strip * RS : (OH - RS);   // ragged: recompute overlap

    char* const pImg = lds;
    char* const pFlt = lds + FLT_OFF;
    const char* bB = pImg + kg * IMG_PLANE + (2 * wv + ysub) * IMG_ROW + xl * 16;
    const char* bA = pFlt + kg * FLT_PLANE + sub * 16;

    f32x4 acc[2][7];
    #pragma unroll
    for (int m = 0; m < 2; ++m)
        #pragma unroll
        for (int nf = 0; nf < 7; ++nf) acc[m][nf] = (f32x4)0.0f;

    for (int c = 0; c < 4; ++c) {
        const int ci0 = c * 32;
        if (c) __syncthreads();
        // ---- stage img: 10 rows x 56 cols, 64B per site -> 4 oct planes ----
        for (int i = tid; i < 10 * WW; i += 256) {
            const int r = i / WW, x = i - r * WW;
            const unsigned short* src =
                imgT + ((size_t)((b * HH + ystart + r) * WW + x)) * CIN + ci0;
            u16x8 v0 = *(const u16x8*)(src);
            u16x8 v1 = *(const u16x8*)(src + 8);
            u16x8 v2 = *(const u16x8*)(src + 16);
            u16x8 v3 = *(const u16x8*)(src + 24);
            char* dst = pImg + r * IMG_ROW + x * 16;
            *(u16x8*)(dst + 0 * IMG_PLANE) = v0;
            *(u16x8*)(dst + 1 * IMG_PLANE) = v1;
            *(u16x8*)(dst + 2 * IMG_PLANE) = v2;
            *(u16x8*)(dst + 3 * IMG_PLANE) = v3;
        }
        // ---- stage filters part A: taps 0..4 (tp 0..9), 320 sites ----
        for (int i = tid; i < 320; i += 256) {
            const int cc = i & 31, tpl = i >> 5;
            const unsigned short* src =
                filtT + ((size_t)(tpl * COUT + co0 + cc)) * CIN + ci0;
            u16x8 v0 = *(const u16x8*)(src);
            u16x8 v1 = *(const u16x8*)(src + 8);
            u16x8 v2 = *(const u16x8*)(src + 16);
            u16x8 v3 = *(const u16x8*)(src + 24);
            char* dst = pFlt + tpl * 512 + cc * 16;
            *(u16x8*)(dst + 0 * FLT_PLANE) = v0;
            *(u16x8*)(dst + 1 * FLT_PLANE) = v1;
            *(u16x8*)(dst + 2 * FLT_PLANE) = v2;
            *(u16x8*)(dst + 3 * FLT_PLANE) = v3;
        }
        __syncthreads();
        compute_taps<0, 5, 0>(bA, bB, acc);
        __syncthreads();
        // ---- stage filters part B: taps 5..8 (tp 10..17), 256 sites ----
        {
            const int i = tid;
            const int cc = i & 31, tpl = i >> 5;   // tpl 0..7
            const unsigned short* src =
                filtT + ((size_t)((tpl + 10) * COUT + co0 + cc)) * CIN + ci0;
            u16x8 v0 = *(const u16x8*)(src);
            u16x8 v1 = *(const u16x8*)(src + 8);
            u16x8 v2 = *(const u16x8*)(src + 16);
            u16x8 v3 = *(const u16x8*)(src + 24);
            char* dst = pFlt + tpl * 512 + cc * 16;
            *(u16x8*)(dst + 0 * FLT_PLANE) = v0;
            *(u16x8*)(dst + 1 * FLT_PLANE) = v1;
            *(u16x8*)(dst + 2 * FLT_PLANE) = v2;
            *(u16x8*)(dst + 3 * FLT_PLANE) = v3;
        }
        __syncthreads();
        compute_taps<5, 9, 5>(bA, bB, acc);
    }

    // ---- epilogue: D col = lane&15 -> spatial, row = kg*4+j -> co ----
    const int y = ystart + 2 * wv + ysub;
    #pragma unroll
    for (int m = 0; m < 2; ++m) {
        const int cob = co0 + m * 16 + kg * 4;
        #pragma unroll
        for (int nf = 0; nf < 7; ++nf) {
            const int x = nf * 8 + xl;
            if (x < OW) {
                float* o = out + ((size_t)(b * COUT + cob) * OH + y) * OW + x;
                #pragma unroll
                for (int j = 0; j < 4; ++j)
                    o[(size_t)j * OH * OW] = acc[m][nf][j];
            }
        }
    }
}

// ---------------- fp32 fallback (ws too small) ------------------------------
#define COB  16
#define THF  6
#define CIBF 2
#define IRF  (THF + 2)
__global__ __launch_bounds__(256) void conv3x3_fp32(
    const float* __restrict__ img, const float* __restrict__ flt,
    float* __restrict__ out)
{
    __shared__ float si[CIBF][IRF][WW];
    __shared__ float sf[CIBF][COB][9];
    const int tid = threadIdx.x;
    const int tx  = tid & 63;
    const int tg  = tid >> 6;
    int bid = blockIdx.x;
    const int ytile = bid % (OH / THF);  bid /= (OH / THF);
    const int cob   = bid % (COUT / COB); bid /= (COUT / COB);
    const int b     = bid;
    const int y0  = ytile * THF;
    const int co0 = cob * COB;
    float acc[4][THF];
    #pragma unroll
    for (int c = 0; c < 4; ++c)
        #pragma unroll
        for (int y = 0; y < THF; ++y) acc[c][y] = 0.0f;
    for (int ci0 = 0; ci0 < CIN; ci0 += CIBF) {
        for (int i = tid; i < CIBF * IRF * (WW / 4); i += 256) {
            const int cil = i / (IRF * (WW / 4));
            int rem = i - cil * (IRF * (WW / 4));
            const int r = rem / (WW / 4);
            const int v = rem - r * (WW / 4);
            const float4* src = reinterpret_cast<const float4*>(
                img + (((size_t)b * CIN + (ci0 + cil)) * HH + (y0 + r)) * WW) + v;
            reinterpret_cast<float4*>(&si[cil][r][0])[v] = *src;
        }
        for (int i = tid; i < CIBF * COB * 9; i += 256) {
            const int cil = i / (COB * 9);
            int rem = i - cil * (COB * 9);
            const int col = rem / 9;
            const int e   = rem - col * 9;
            sf[cil][col][e] = flt[(((size_t)(co0 + col)) * CIN + (ci0 + cil)) * 9 + e];
        }
        __syncthreads();
        if (tx < OW) {
            #pragma unroll
            for (int cil = 0; cil < CIBF; ++cil) {
                float f[4][9];
                #pragma unroll
                for (int c = 0; c < 4; ++c)
                    #pragma unroll
                    for (int e = 0; e < 9; ++e) f[c][e] = sf[cil][tg * 4 + c][e];
                float a[IRF][3];
                #pragma unroll
                for (int r = 0; r < IRF; ++r) {
                    a[r][0] = si[cil][r][tx + 0];
                    a[r][1] = si[cil][r][tx + 1];
                    a[r][2] = si[cil][r][tx + 2];
                }
                #pragma unroll
                for (int y = 0; y < THF; ++y)
                    #pragma unroll
                    for (int dy = 0; dy < 3; ++dy)
                        #pragma unroll
                        for (int c = 0; c < 4; ++c)
                            acc[c][y] = fmaf(a[y + dy][0], f[c][dy * 3 + 0],
                                        fmaf(a[y + dy][1], f[c][dy * 3 + 1],
                                        fmaf(a[y + dy][2], f[c][dy * 3 + 2], acc[c][y])));
            }
        }
        __syncthreads();
    }
    if (tx < OW) {
        #pragma unroll
        for (int c = 0; c < 4; ++c) {
            const int co = co0 + tg * 4 + c;
            #pragma unroll
            for (int y = 0; y < THF; ++y)
                out[(((size_t)b * COUT + co) * OH + (y0 + y)) * OW + tx] = acc[c][y];
        }
    }
}

extern "C" void kernel_launch(void* const* d_in, const int* in_sizes, int n_in,
                              void* d_out, int out_size, void* d_ws, size_t ws_size,
                              hipStream_t stream) {
    const float* img = (const float*)d_in[0];
    const float* flt = (const float*)d_in[1];
    float* out = (float*)d_out;

    const size_t IMGT_BYTES = (size_t)BB * HH * WW * CIN * 2;        // 25,690,112
    const size_t FILT_BYTES = (size_t)18 * COUT * CIN * 2;           //  1,179,648
    if (ws_size < IMGT_BYTES + FILT_BYTES) {
        // fallback: direct fp32
        conv3x3_fp32<<<BB * (COUT / COB) * (OH / THF), 256, 0, stream>>>(img, flt, out);
        return;
    }
    unsigned short* imgT  = (unsigned short*)d_ws;
    unsigned short* filtT = (unsigned short*)((char*)d_ws + IMGT_BYTES);

    prep_img<<<BB * HH, 256, 0, stream>>>(img, imgT);
    prep_flt<<<(COUT * CIN) / 256, 256, 0, stream>>>(flt, filtT);
    conv_mfma<<<8 * 7 * BB, 256, 0, stream>>>(imgT, filtT, out);
}